// Round 15
// baseline (95.307 us; speedup 1.0000x reference)
//
#include <hip/hip_runtime.h>
#include <math.h>

// ---------------------------------------------------------------------------
// Encoder_Flows on MI355X — 5 dispatches (R14 = 90.8us base).
//   prep  : blocks 0-31 proj1 (dbuf) -> YT1 + T1; blocks 32-351 weight cvt.
//   main_L: 1024x32-row blocks: tail = staged GEMM + norm.
//       Head tile m: agg = (P + local)/cnt (P from per-tile T sums, local =
//       ONE triangular step). Heads then run the next layer's proj on their
//       own just-stored rows (staged, coalesced) -> YT_next + T_next.
// R15 changes vs R14 (polish): DIN is a template param (static k-loop trip
// counts -> compiler unroll/pipeline, biggest effect on 2-4-step mains);
// MINW 3->4 for DOUT=256 mains (37.5KB LDS -> 4 blocks/CU fit).
// Laws: no spin sync; no direct-frag global loads; no in-block layer chains;
// head-extra work must be coalesced + small.
// ---------------------------------------------------------------------------

typedef __attribute__((ext_vector_type(8))) short short8;
typedef __attribute__((ext_vector_type(4))) float f32x4;

constexpr int NROWS = 32768;
constexpr int KROWS = 1024;

static __device__ __forceinline__ unsigned short f2bf(float f) {
    unsigned int u = __float_as_uint(f);
    return (unsigned short)((u + 0x7fffu + ((u >> 16) & 1u)) >> 16);
}

// ---- register staging helpers (tile ROWS x 64, XOR-swizzled LDS) ----------
template<int ROWS>
struct RegsBF {
    short8 v[ROWS / 32];
    __device__ __forceinline__ void load(const unsigned short* src, int ld,
                                         int r0, int k0, int t) {
#pragma unroll
        for (int j = 0; j < ROWS / 32; ++j) {
            int idx = j * 256 + t; int r = idx >> 3, f = idx & 7;
            v[j] = *reinterpret_cast<const short8*>(
                src + (size_t)(r0 + r) * ld + k0 + f * 8);
        }
    }
    __device__ __forceinline__ void store(unsigned short* buf, int t) {
#pragma unroll
        for (int j = 0; j < ROWS / 32; ++j) {
            int idx = j * 256 + t; int r = idx >> 3, f = idx & 7;
            int off = (r * 128 + f * 16) ^ ((r & 7) << 4);
            *reinterpret_cast<short8*>((char*)buf + off) = v[j];
        }
    }
};

template<int ROWS>
struct RegsF32 {
    float4 v[ROWS / 16];
    __device__ __forceinline__ void load(const float* src, int ld,
                                         int r0, int k0, int t) {
#pragma unroll
        for (int j = 0; j < ROWS / 32; ++j) {
            int idx = j * 256 + t; int r = idx >> 3, f = idx & 7;
            const float* p = src + (size_t)(r0 + r) * ld + k0 + f * 8;
            v[2 * j]     = *reinterpret_cast<const float4*>(p);
            v[2 * j + 1] = *reinterpret_cast<const float4*>(p + 4);
        }
    }
    __device__ __forceinline__ void store(unsigned short* buf, int t) {
#pragma unroll
        for (int j = 0; j < ROWS / 32; ++j) {
            int idx = j * 256 + t; int r = idx >> 3, f = idx & 7;
            float4 a = v[2 * j], b = v[2 * j + 1];
            short8 s;
            s[0] = (short)f2bf(a.x); s[1] = (short)f2bf(a.y);
            s[2] = (short)f2bf(a.z); s[3] = (short)f2bf(a.w);
            s[4] = (short)f2bf(b.x); s[5] = (short)f2bf(b.y);
            s[6] = (short)f2bf(b.z); s[7] = (short)f2bf(b.w);
            int off = (r * 128 + f * 16) ^ ((r & 7) << 4);
            *reinterpret_cast<short8*>((char*)buf + off) = s;
        }
    }
};

// ---- per-tile fragment read + MFMA over one 64-k LDS tile ------------------
template<int BM, int WM, int WN, int FM>
__device__ __forceinline__ void mfma_tile(const unsigned short* Abuf,
    const unsigned short* Bbuf, f32x4 (&acc)[FM][4], int wr_, int wc, int lane)
{
#pragma unroll
    for (int kk = 0; kk < 2; ++kk) {
        short8 a[FM], b[4];
#pragma unroll
        for (int fi = 0; fi < FM; ++fi) {
            const int rA = wr_ * (BM / WM) + fi * 16 + (lane & 15);
            const int off = (rA * 128 + kk * 64 + (lane >> 4) * 16) ^ ((rA & 7) << 4);
            a[fi] = *reinterpret_cast<const short8*>((const char*)Abuf + off);
        }
#pragma unroll
        for (int fj = 0; fj < 4; ++fj) {
            const int rB = wc * 64 + fj * 16 + (lane & 15);
            const int off = (rB * 128 + kk * 64 + (lane >> 4) * 16) ^ ((rB & 7) << 4);
            b[fj] = *reinterpret_cast<const short8*>((const char*)Bbuf + off);
        }
#pragma unroll
        for (int fi = 0; fi < FM; ++fi)
#pragma unroll
            for (int fj = 0; fj < 4; ++fj)
                acc[fi][fj] = __builtin_amdgcn_mfma_f32_16x16x32_bf16(
                    a[fi], b[fj], acc[fi][fj], 0, 0, 0);
    }
}

// ---- 2-barrier staged GEMM, static trip count (bf16 A) ----------------------
template<int DIN, int DOUT>
__device__ __forceinline__ void bulk_gemm_bf(const unsigned short* __restrict__ Av,
    const unsigned short* __restrict__ W, f32x4 (&acc)[DOUT / 128][4],
    unsigned short* Abuf, unsigned short* Bbuf, int t)
{
    constexpr int WN = DOUT / 64, WM = 4 / WN, FM = DOUT / 128, NT = DIN / 64;
    const int wv = t >> 6, lane = t & 63, wr_ = wv / WN, wc = wv % WN;
#pragma unroll
    for (int fi = 0; fi < FM; ++fi)
#pragma unroll
        for (int fj = 0; fj < 4; ++fj) acc[fi][fj] = (f32x4){0.f, 0.f, 0.f, 0.f};
    RegsBF<32> arb; RegsBF<DOUT> brg;
    arb.load(Av, DIN, 0, 0, t);
    brg.load(W, DIN, 0, 0, t);
    for (int kt = 0; kt < NT; ++kt) {
        if (kt) __syncthreads();
        arb.store(Abuf, t);
        brg.store(Bbuf, t);
        __syncthreads();
        if (kt + 1 < NT) {
            const int kn = (kt + 1) * 64;
            arb.load(Av, DIN, 0, kn, t);
            brg.load(W, DIN, 0, kn, t);
        }
        mfma_tile<32, WM, WN, FM>(Abuf, Bbuf, acc, wr_, wc, lane);
    }
}

// ---- proj epilogues: YT (bf16 transposed) + T (fp32 column sums) -----------
template<int DOUT>
__device__ __forceinline__ void proj_epilogue(const f32x4 (&acc)[DOUT / 128][4],
    unsigned short* __restrict__ YT, float* __restrict__ Tg, int i0,
    float* Tred, int t)
{
    constexpr int WN = DOUT / 64, WM = 4 / WN, FM = DOUT / 128;
    const int wv = t >> 6, lane = t & 63, wr_ = wv / WN, wc = wv % WN;
#pragma unroll
    for (int fi = 0; fi < FM; ++fi)
#pragma unroll
        for (int fj = 0; fj < 4; ++fj) {
            const int rl0 = wr_ * (32 / WM) + fi * 16 + ((lane >> 4) << 2);
            const int cl  = wc * 64 + fj * 16 + (lane & 15);
            ushort4 y;
            y.x = f2bf(acc[fi][fj][0]); y.y = f2bf(acc[fi][fj][1]);
            y.z = f2bf(acc[fi][fj][2]); y.w = f2bf(acc[fi][fj][3]);
            *reinterpret_cast<ushort4*>(YT + (size_t)cl * KROWS + i0 + rl0) = y;
        }
    float v[4];
#pragma unroll
    for (int fj = 0; fj < 4; ++fj) {
        float s = 0.f;
#pragma unroll
        for (int fi = 0; fi < FM; ++fi)
#pragma unroll
            for (int reg = 0; reg < 4; ++reg) s += acc[fi][fj][reg];
        s += __shfl_xor(s, 16);
        s += __shfl_xor(s, 32);
        v[fj] = s;
    }
    if (lane < 16) {
#pragma unroll
        for (int fj = 0; fj < 4; ++fj)
            Tred[wr_ * DOUT + wc * 64 + fj * 16 + lane] = v[fj];
    }
    __syncthreads();
    if (t < DOUT) {
        float s = Tred[t];
        if constexpr (WM == 2) s += Tred[DOUT + t];
        Tg[t] = s;
    }
}

// ---------------------------------------------------------------------------
// Proj body (prep only): dbuf-pipelined, fp32 A and B.
// ---------------------------------------------------------------------------
__device__ __forceinline__ void proj1_dbuf(const float* __restrict__ flow,
    const float* __restrict__ wl1, unsigned short* __restrict__ YT1,
    float* __restrict__ Tg, int i0, int t,
    unsigned short* Ab0, unsigned short* Ab1,
    unsigned short* Bb0, unsigned short* Bb1, float* Tred)
{
    const int wv = t >> 6, lane = t & 63, wr_ = wv >> 1, wc = wv & 1;
    f32x4 acc[1][4];
#pragma unroll
    for (int fj = 0; fj < 4; ++fj) acc[0][fj] = (f32x4){0.f, 0.f, 0.f, 0.f};
    RegsF32<32> ar; RegsF32<128> br;
    ar.load(flow, 1024, i0, 0, t);
    br.load(wl1, 1024, 0, 0, t);
    ar.store(Ab0, t); br.store(Bb0, t);
    ar.load(flow, 1024, i0, 64, t);
    br.load(wl1, 1024, 0, 64, t);
    __syncthreads();
    for (int kt = 0; kt < 16; ++kt) {
        const unsigned short* Ac = (kt & 1) ? Ab1 : Ab0;
        const unsigned short* Bc = (kt & 1) ? Bb1 : Bb0;
        mfma_tile<32, 2, 2, 1>(Ac, Bc, acc, wr_, wc, lane);
        if (kt + 1 < 16) {
            unsigned short* An = (kt & 1) ? Ab0 : Ab1;
            unsigned short* Bn = (kt & 1) ? Bb0 : Bb1;
            ar.store(An, t); br.store(Bn, t);
            if (kt + 2 < 16) {
                ar.load(flow, 1024, i0, (kt + 2) * 64, t);
                br.load(wl1, 1024, 0, (kt + 2) * 64, t);
            }
        }
        __syncthreads();
    }
    proj_epilogue<128>(acc, YT1, Tg, i0, Tred, t);
}

// ---------------------------------------------------------------------------
// prep: blocks [0,32) proj1 -> YT1 + T1; blocks [32,352) weight cvt; scalar.
// ---------------------------------------------------------------------------
__global__ __launch_bounds__(256, 2)
void prep_kernel(const float* __restrict__ flow, const float* __restrict__ wl1,
                 const float* __restrict__ wr1, const float* __restrict__ wl2,
                 const float* __restrict__ wr2, const float* __restrict__ wl3,
                 const float* __restrict__ wr3, const float* __restrict__ wl4,
                 const float* __restrict__ wr4,
                 unsigned short* __restrict__ wbf,
                 unsigned short* __restrict__ YT1, float* __restrict__ T1,
                 float* __restrict__ outscalar)
{
    __shared__ unsigned short Ab0[32 * 64], Ab1[32 * 64];
    __shared__ unsigned short Bb0[128 * 64], Bb1[128 * 64];
    __shared__ float Tred[256];
    const int t = threadIdx.x, bid = blockIdx.x;
    if (bid >= 32) {
        if (bid == 32 && t == 0) outscalar[0] = 1.0f;
        int g = (bid - 32) * 1024 + t * 4;
        const float* src; int off;
        if      (g < 131072) { src = wr1; off = g; }
        else if (g < 163840) { src = wl2; off = g - 131072; }
        else if (g < 196608) { src = wr2; off = g - 163840; }
        else if (g < 229376) { src = wl3; off = g - 196608; }
        else if (g < 262144) { src = wr3; off = g - 229376; }
        else if (g < 294912) { src = wl4; off = g - 262144; }
        else                 { src = wr4; off = g - 294912; }
        float4 v = *reinterpret_cast<const float4*>(src + off);
        ushort4 o4;
        o4.x = f2bf(v.x); o4.y = f2bf(v.y); o4.z = f2bf(v.z); o4.w = f2bf(v.w);
        *reinterpret_cast<ushort4*>(wbf + g) = o4;
        return;
    }
    proj1_dbuf(flow, wl1, YT1, T1 + bid * 128, bid * 32, t,
               Ab0, Ab1, Bb0, Bb1, Tred);
}

// ---------------------------------------------------------------------------
// main_L.  MODE 1: bf16 x out (+ head: next-layer proj).  MODE 2: relu->fp32.
// DIN is compile-time -> static k-loop trip counts (unroll/pipeline).
// ---------------------------------------------------------------------------
template<int DIN, int DOUT, int MODE, bool AFP32, int MINW, int DNEXT>
__global__ __launch_bounds__(256, MINW)
void mfma_gemm(const void* __restrict__ Xv,
               const unsigned short* __restrict__ W,
               const float* __restrict__ bias,
               const unsigned short* __restrict__ YT,  // (DOUT, 1024) bf16
               const float* __restrict__ Tbuf,         // (32, DOUT) fp32
               float* __restrict__ outf,
               unsigned short* __restrict__ outb,
               const unsigned short* __restrict__ Wn,  // next wl (bf16)
               unsigned short* __restrict__ YTn, float* __restrict__ Tn)
{
    constexpr int BM = 32, BN = DOUT, NT = DIN / 64;
    constexpr int WN = DOUT / 64, WM = 4 / WN, FM = DOUT / 128;
    constexpr int BB = (DNEXT > BN ? DNEXT : BN);
    __shared__ unsigned short Abuf[BM * 64];
    __shared__ unsigned short Bbuf[BB * 64];
    __shared__ float ssred[WN * BM];
    __shared__ float Tred[256];

    const int t = threadIdx.x, wvid = t >> 6, lane = t & 63;
    const int wr_ = wvid / WN, wc = wvid % WN;
    const int i0 = blockIdx.x * BM;
    const bool hasagg = (i0 < KROWS);

    f32x4 agg[FM][4];
#pragma unroll
    for (int fi = 0; fi < FM; ++fi)
#pragma unroll
        for (int fj = 0; fj < 4; ++fj) agg[fi][fj] = (f32x4){0.f, 0.f, 0.f, 0.f};

    if (hasagg) {
        // ---- P[col] = sum_{m'<m} T[m'][col] ----
        const int m = i0 >> 5;
        const int colb = wc * 64 + (lane & 15);
        float Pv[4] = {0.f, 0.f, 0.f, 0.f}, Pa[4] = {0.f, 0.f, 0.f, 0.f};
        int mp = 0;
        for (; mp + 1 < m; mp += 2) {
            const float* T0 = Tbuf + (size_t)mp * DOUT + colb;
            const float* T1p = T0 + DOUT;
#pragma unroll
            for (int fj = 0; fj < 4; ++fj) {
                Pv[fj] += T0[fj * 16];
                Pa[fj] += T1p[fj * 16];
            }
        }
        if (mp < m) {
            const float* T0 = Tbuf + (size_t)mp * DOUT + colb;
#pragma unroll
            for (int fj = 0; fj < 4; ++fj) Pv[fj] += T0[fj * 16];
        }
#pragma unroll
        for (int fj = 0; fj < 4; ++fj) Pv[fj] += Pa[fj];

        // ---- local triangular: ONE staged step over YT cols [base,base+64) -
        const int base = i0 & ~63;
        RegsBF<BN> sb;
        sb.load(YT, KROWS, 0, base, t);
        sb.store(Bbuf, t);
        __syncthreads();
#pragma unroll
        for (int kk = 0; kk < 2; ++kk) {
            const int jb = base + kk * 32 + ((lane >> 4) << 3);
            short8 a[FM], b[4];
#pragma unroll
            for (int fi = 0; fi < FM; ++fi) {
                const int irow = i0 + wr_ * (BM / WM) + fi * 16 + (lane & 15);
#pragma unroll
                for (int e = 0; e < 8; ++e)
                    a[fi][e] = (short)((jb + e >= i0 && jb + e < irow) ? 0x3F80 : 0);
            }
#pragma unroll
            for (int fj = 0; fj < 4; ++fj) {
                const int rB = wc * 64 + fj * 16 + (lane & 15);
                const int off = (rB * 128 + kk * 64 + (lane >> 4) * 16) ^ ((rB & 7) << 4);
                b[fj] = *reinterpret_cast<const short8*>((const char*)Bbuf + off);
            }
#pragma unroll
            for (int fi = 0; fi < FM; ++fi)
#pragma unroll
                for (int fj = 0; fj < 4; ++fj)
                    agg[fi][fj] = __builtin_amdgcn_mfma_f32_16x16x32_bf16(
                        a[fi], b[fj], agg[fi][fj], 0, 0, 0);
        }
#pragma unroll
        for (int fi = 0; fi < FM; ++fi)
#pragma unroll
            for (int reg = 0; reg < 4; ++reg) {
                const int i_abs = i0 + wr_ * (BM / WM) + fi * 16 + ((lane >> 4) << 2) + reg;
                const float inv = 1.0f / (float)(i_abs > 1 ? i_abs : 1);
#pragma unroll
                for (int fj = 0; fj < 4; ++fj)
                    agg[fi][fj][reg] = (agg[fi][fj][reg] + Pv[fj]) * inv;
            }
        __syncthreads();                        // Bbuf free before bulk
    }

    // ---- bulk GEMM (2-barrier staged core, static NT) ----
    f32x4 acc[FM][4];
#pragma unroll
    for (int fi = 0; fi < FM; ++fi)
#pragma unroll
        for (int fj = 0; fj < 4; ++fj) acc[fi][fj] = (f32x4){0.f, 0.f, 0.f, 0.f};

    RegsBF<BN> brg;
    RegsF32<BM> arf;
    RegsBF<BM> arb;
    if (AFP32) arf.load((const float*)Xv, DIN, i0, 0, t);
    else       arb.load((const unsigned short*)Xv, DIN, i0, 0, t);
    brg.load(W, DIN, 0, 0, t);

    for (int kt = 0; kt < NT; ++kt) {
        if (kt) __syncthreads();
        if (AFP32) arf.store(Abuf, t); else arb.store(Abuf, t);
        brg.store(Bbuf, t);
        __syncthreads();
        if (kt + 1 < NT) {
            int kn = (kt + 1) * 64;
            if (AFP32) arf.load((const float*)Xv, DIN, i0, kn, t);
            else       arb.load((const unsigned short*)Xv, DIN, i0, kn, t);
            brg.load(W, DIN, 0, kn, t);
        }
        mfma_tile<BM, WM, WN, FM>(Abuf, Bbuf, acc, wr_, wc, lane);
    }

    float bb[4];
#pragma unroll
    for (int fj = 0; fj < 4; ++fj) bb[fj] = bias[wc * 64 + fj * 16 + (lane & 15)];

#pragma unroll
    for (int fi = 0; fi < FM; ++fi)
#pragma unroll
        for (int fj = 0; fj < 4; ++fj)
#pragma unroll
            for (int reg = 0; reg < 4; ++reg)
                acc[fi][fj][reg] += bb[fj] + agg[fi][fj][reg];

    float sstot[FM][4];
#pragma unroll
    for (int fi = 0; fi < FM; ++fi)
#pragma unroll
        for (int reg = 0; reg < 4; ++reg) {
            float s = 0.f;
#pragma unroll
            for (int fj = 0; fj < 4; ++fj) {
                float v = acc[fi][fj][reg];
                s += v * v;
            }
#pragma unroll
            for (int m2 = 8; m2 >= 1; m2 >>= 1) s += __shfl_xor(s, m2);
            if ((lane & 15) == 0) {
                int rl = wr_ * (BM / WM) + fi * 16 + ((lane >> 4) << 2) + reg;
                ssred[wc * BM + rl] = s;
            }
        }
    __syncthreads();
#pragma unroll
    for (int fi = 0; fi < FM; ++fi)
#pragma unroll
        for (int reg = 0; reg < 4; ++reg) {
            int rl = wr_ * (BM / WM) + fi * 16 + ((lane >> 4) << 2) + reg;
            float s = 0.f;
#pragma unroll
            for (int c = 0; c < WN; ++c) s += ssred[c * BM + rl];
            sstot[fi][reg] = 1.0f / fmaxf(sqrtf(s), 1e-12f);
        }

#pragma unroll
    for (int fi = 0; fi < FM; ++fi)
#pragma unroll
        for (int fj = 0; fj < 4; ++fj)
#pragma unroll
            for (int reg = 0; reg < 4; ++reg) {
                int rl = wr_ * (BM / WM) + fi * 16 + ((lane >> 4) << 2) + reg;
                int cl = wc * 64 + fj * 16 + (lane & 15);
                float v = acc[fi][fj][reg] * sstot[fi][reg];
                if (MODE == 2) {
                    v = fmaxf(v, 0.f);
                    outf[(size_t)(i0 + rl) * DOUT + cl] = v;
                } else {
                    outb[(size_t)(i0 + rl) * DOUT + cl] = f2bf(v);
                }
            }

    // ---- head: next-layer proj on own just-stored rows ----
    if constexpr (DNEXT > 0) {
        if (hasagg) {
            __syncthreads();        // drain x stores (vmcnt0 at barrier)
            f32x4 acc2[DNEXT / 128][4];
            bulk_gemm_bf<DOUT, DNEXT>(outb + (size_t)i0 * DOUT, Wn, acc2,
                                      Abuf, Bbuf, t);
            __syncthreads();        // Tred reuse safety (after ssred phase)
            proj_epilogue<DNEXT>(acc2, YTn, Tn + (i0 >> 5) * DNEXT, i0, Tred, t);
        }
    }
}

extern "C" void kernel_launch(void* const* d_in, const int* in_sizes, int n_in,
                              void* d_out, int out_size, void* d_ws, size_t ws_size,
                              hipStream_t stream)
{
    const float* flow = (const float*)d_in[0];
    const float* wl1 = (const float*)d_in[1];
    const float* bl1 = (const float*)d_in[2];
    const float* wr1 = (const float*)d_in[3];
    const float* wl2 = (const float*)d_in[4];
    const float* bl2 = (const float*)d_in[5];
    const float* wr2 = (const float*)d_in[6];
    const float* wl3 = (const float*)d_in[7];
    const float* bl3 = (const float*)d_in[8];
    const float* wr3 = (const float*)d_in[9];
    const float* wl4 = (const float*)d_in[10];
    const float* bl4 = (const float*)d_in[11];
    const float* wr4 = (const float*)d_in[12];
    float* out = (float*)d_out;

    char* p = (char*)d_ws;
    unsigned short* wbf = (unsigned short*)p;  p += 1 << 20;
    unsigned short* xA  = (unsigned short*)p;  p += (size_t)NROWS * 128 * 2;
    unsigned short* xB  = (unsigned short*)p;  p += (size_t)NROWS * 256 * 2;
    unsigned short* YT1 = (unsigned short*)p;  p += (size_t)128 * KROWS * 2;
    unsigned short* YT2 = (unsigned short*)p;  p += (size_t)256 * KROWS * 2;
    unsigned short* YT3 = (unsigned short*)p;  p += (size_t)128 * KROWS * 2;
    unsigned short* YT4 = (unsigned short*)p;  p += (size_t)256 * KROWS * 2;
    float* T1 = (float*)p;                     p += (size_t)32 * 128 * 4;
    float* T2 = (float*)p;                     p += (size_t)32 * 256 * 4;
    float* T3 = (float*)p;                     p += (size_t)32 * 128 * 4;
    float* T4 = (float*)p;

    const unsigned short* wr1b = wbf;
    const unsigned short* wl2b = wbf + 131072;
    const unsigned short* wr2b = wbf + 163840;
    const unsigned short* wl3b = wbf + 196608;
    const unsigned short* wr3b = wbf + 229376;
    const unsigned short* wl4b = wbf + 262144;
    const unsigned short* wr4b = wbf + 294912;

    // D1: cvt + proj1 (+ tuple scalar)
    prep_kernel<<<352, 256, 0, stream>>>(flow, wl1, wr1, wl2, wr2, wl3, wr3,
                                         wl4, wr4, wbf, YT1, T1,
                                         out + (size_t)NROWS * 256);
    // D2: main L1 (din=1024, fp32 A); heads emit proj2 -> YT2,T2
    mfma_gemm<1024, 128, 1, true , 4, 256><<<1024, 256, 0, stream>>>(
        flow, wr1b, bl1, YT1, T1, nullptr, xA, wl2b, YT2, T2);
    // D3: main L2 (din=128); heads emit proj3 -> YT3,T3
    mfma_gemm< 128, 256, 1, false, 4, 128><<<1024, 256, 0, stream>>>(
        xA, wr2b, bl2, YT2, T2, nullptr, xB, wl3b, YT3, T3);
    // D4: main L3 (din=256); heads emit proj4 -> YT4,T4
    mfma_gemm< 256, 128, 1, false, 4, 256><<<1024, 256, 0, stream>>>(
        xB, wr3b, bl3, YT3, T3, nullptr, xA, wl4b, YT4, T4);
    // D5: main L4 (din=128) + relu -> fp32 out
    mfma_gemm< 128, 256, 2, false, 4, 0><<<1024, 256, 0, stream>>>(
        xA, wr4b, bl4, YT4, T4, out, nullptr, nullptr, nullptr, nullptr);
}

// Round 16
// 90.887 us; speedup vs baseline: 1.0486x; 1.0486x over previous
//
#include <hip/hip_runtime.h>
#include <math.h>

// ---------------------------------------------------------------------------
// Encoder_Flows on MI355X — 5 dispatches (R14 = 90.8us, reverted from R15).
//   prep  : blocks 0-31 proj1 (dbuf) -> YT1 + T1; blocks 32-351 weight cvt.
//   main_L: 1024x32-row blocks (R13 core): tail = staged GEMM + norm.
//       Head tile m: agg = (P + local)/cnt  (P from per-tile T sums, local =
//       ONE triangular step). Heads then run the NEXT layer's proj on their
//       own just-stored rows (staged bulk_gemm, coalesced W staging),
//       writing YT_next + T_next.
// R15 lesson: MINW=4 on DOUT=256 mains (VGPR cap -> spills) and full static
// k-loop unroll both regressed (-4.5us). Reverted; runtime din + MINW {4,3}.
// Laws: no spin sync; no direct-frag global loads; no in-block layer chains;
// head-extra work must be coalesced + small; occupancy before pipelining;
// one variable per experiment.
// ---------------------------------------------------------------------------

typedef __attribute__((ext_vector_type(8))) short short8;
typedef __attribute__((ext_vector_type(4))) float f32x4;

constexpr int NROWS = 32768;
constexpr int KROWS = 1024;

static __device__ __forceinline__ unsigned short f2bf(float f) {
    unsigned int u = __float_as_uint(f);
    return (unsigned short)((u + 0x7fffu + ((u >> 16) & 1u)) >> 16);
}

// ---- register staging helpers (tile ROWS x 64, XOR-swizzled LDS) ----------
template<int ROWS>
struct RegsBF {
    short8 v[ROWS / 32];
    __device__ __forceinline__ void load(const unsigned short* src, int ld,
                                         int r0, int k0, int t) {
#pragma unroll
        for (int j = 0; j < ROWS / 32; ++j) {
            int idx = j * 256 + t; int r = idx >> 3, f = idx & 7;
            v[j] = *reinterpret_cast<const short8*>(
                src + (size_t)(r0 + r) * ld + k0 + f * 8);
        }
    }
    __device__ __forceinline__ void store(unsigned short* buf, int t) {
#pragma unroll
        for (int j = 0; j < ROWS / 32; ++j) {
            int idx = j * 256 + t; int r = idx >> 3, f = idx & 7;
            int off = (r * 128 + f * 16) ^ ((r & 7) << 4);
            *reinterpret_cast<short8*>((char*)buf + off) = v[j];
        }
    }
};

template<int ROWS>
struct RegsF32 {
    float4 v[ROWS / 16];
    __device__ __forceinline__ void load(const float* src, int ld,
                                         int r0, int k0, int t) {
#pragma unroll
        for (int j = 0; j < ROWS / 32; ++j) {
            int idx = j * 256 + t; int r = idx >> 3, f = idx & 7;
            const float* p = src + (size_t)(r0 + r) * ld + k0 + f * 8;
            v[2 * j]     = *reinterpret_cast<const float4*>(p);
            v[2 * j + 1] = *reinterpret_cast<const float4*>(p + 4);
        }
    }
    __device__ __forceinline__ void store(unsigned short* buf, int t) {
#pragma unroll
        for (int j = 0; j < ROWS / 32; ++j) {
            int idx = j * 256 + t; int r = idx >> 3, f = idx & 7;
            float4 a = v[2 * j], b = v[2 * j + 1];
            short8 s;
            s[0] = (short)f2bf(a.x); s[1] = (short)f2bf(a.y);
            s[2] = (short)f2bf(a.z); s[3] = (short)f2bf(a.w);
            s[4] = (short)f2bf(b.x); s[5] = (short)f2bf(b.y);
            s[6] = (short)f2bf(b.z); s[7] = (short)f2bf(b.w);
            int off = (r * 128 + f * 16) ^ ((r & 7) << 4);
            *reinterpret_cast<short8*>((char*)buf + off) = s;
        }
    }
};

// ---- per-tile fragment read + MFMA over one 64-k LDS tile ------------------
template<int BM, int WM, int WN, int FM>
__device__ __forceinline__ void mfma_tile(const unsigned short* Abuf,
    const unsigned short* Bbuf, f32x4 (&acc)[FM][4], int wr_, int wc, int lane)
{
#pragma unroll
    for (int kk = 0; kk < 2; ++kk) {
        short8 a[FM], b[4];
#pragma unroll
        for (int fi = 0; fi < FM; ++fi) {
            const int rA = wr_ * (BM / WM) + fi * 16 + (lane & 15);
            const int off = (rA * 128 + kk * 64 + (lane >> 4) * 16) ^ ((rA & 7) << 4);
            a[fi] = *reinterpret_cast<const short8*>((const char*)Abuf + off);
        }
#pragma unroll
        for (int fj = 0; fj < 4; ++fj) {
            const int rB = wc * 64 + fj * 16 + (lane & 15);
            const int off = (rB * 128 + kk * 64 + (lane >> 4) * 16) ^ ((rB & 7) << 4);
            b[fj] = *reinterpret_cast<const short8*>((const char*)Bbuf + off);
        }
#pragma unroll
        for (int fi = 0; fi < FM; ++fi)
#pragma unroll
            for (int fj = 0; fj < 4; ++fj)
                acc[fi][fj] = __builtin_amdgcn_mfma_f32_16x16x32_bf16(
                    a[fi], b[fj], acc[fi][fj], 0, 0, 0);
    }
}

// ---- 2-barrier staged GEMM: acc = A[32 x din] @ W[DOUT x din]^T (bf16 A) ---
template<int DOUT>
__device__ __forceinline__ void bulk_gemm_bf(const unsigned short* __restrict__ Av,
    const unsigned short* __restrict__ W, f32x4 (&acc)[DOUT / 128][4],
    unsigned short* Abuf, unsigned short* Bbuf, int din, int t)
{
    constexpr int WN = DOUT / 64, WM = 4 / WN, FM = DOUT / 128;
    const int wv = t >> 6, lane = t & 63, wr_ = wv / WN, wc = wv % WN;
    const int nt = din >> 6;
#pragma unroll
    for (int fi = 0; fi < FM; ++fi)
#pragma unroll
        for (int fj = 0; fj < 4; ++fj) acc[fi][fj] = (f32x4){0.f, 0.f, 0.f, 0.f};
    RegsBF<32> arb; RegsBF<DOUT> brg;
    arb.load(Av, din, 0, 0, t);
    brg.load(W, din, 0, 0, t);
    for (int kt = 0; kt < nt; ++kt) {
        if (kt) __syncthreads();
        arb.store(Abuf, t);
        brg.store(Bbuf, t);
        __syncthreads();
        if (kt + 1 < nt) {
            const int kn = (kt + 1) * 64;
            arb.load(Av, din, 0, kn, t);
            brg.load(W, din, 0, kn, t);
        }
        mfma_tile<32, WM, WN, FM>(Abuf, Bbuf, acc, wr_, wc, lane);
    }
}

// ---- proj epilogues: YT (bf16 transposed) + T (fp32 column sums) -----------
template<int DOUT>
__device__ __forceinline__ void proj_epilogue(const f32x4 (&acc)[DOUT / 128][4],
    unsigned short* __restrict__ YT, float* __restrict__ Tg, int i0,
    float* Tred, int t)
{
    constexpr int WN = DOUT / 64, WM = 4 / WN, FM = DOUT / 128;
    const int wv = t >> 6, lane = t & 63, wr_ = wv / WN, wc = wv % WN;
#pragma unroll
    for (int fi = 0; fi < FM; ++fi)
#pragma unroll
        for (int fj = 0; fj < 4; ++fj) {
            const int rl0 = wr_ * (32 / WM) + fi * 16 + ((lane >> 4) << 2);
            const int cl  = wc * 64 + fj * 16 + (lane & 15);
            ushort4 y;
            y.x = f2bf(acc[fi][fj][0]); y.y = f2bf(acc[fi][fj][1]);
            y.z = f2bf(acc[fi][fj][2]); y.w = f2bf(acc[fi][fj][3]);
            *reinterpret_cast<ushort4*>(YT + (size_t)cl * KROWS + i0 + rl0) = y;
        }
    float v[4];
#pragma unroll
    for (int fj = 0; fj < 4; ++fj) {
        float s = 0.f;
#pragma unroll
        for (int fi = 0; fi < FM; ++fi)
#pragma unroll
            for (int reg = 0; reg < 4; ++reg) s += acc[fi][fj][reg];
        s += __shfl_xor(s, 16);
        s += __shfl_xor(s, 32);
        v[fj] = s;
    }
    if (lane < 16) {
#pragma unroll
        for (int fj = 0; fj < 4; ++fj)
            Tred[wr_ * DOUT + wc * 64 + fj * 16 + lane] = v[fj];
    }
    __syncthreads();
    if (t < DOUT) {
        float s = Tred[t];
        if constexpr (WM == 2) s += Tred[DOUT + t];
        Tg[t] = s;
    }
}

// ---------------------------------------------------------------------------
// Proj body (prep only): dbuf-pipelined, fp32 A and B.
// ---------------------------------------------------------------------------
__device__ __forceinline__ void proj1_dbuf(const float* __restrict__ flow,
    const float* __restrict__ wl1, unsigned short* __restrict__ YT1,
    float* __restrict__ Tg, int i0, int t,
    unsigned short* Ab0, unsigned short* Ab1,
    unsigned short* Bb0, unsigned short* Bb1, float* Tred)
{
    const int wv = t >> 6, lane = t & 63, wr_ = wv >> 1, wc = wv & 1;
    f32x4 acc[1][4];
#pragma unroll
    for (int fj = 0; fj < 4; ++fj) acc[0][fj] = (f32x4){0.f, 0.f, 0.f, 0.f};
    RegsF32<32> ar; RegsF32<128> br;
    ar.load(flow, 1024, i0, 0, t);
    br.load(wl1, 1024, 0, 0, t);
    ar.store(Ab0, t); br.store(Bb0, t);
    ar.load(flow, 1024, i0, 64, t);
    br.load(wl1, 1024, 0, 64, t);
    __syncthreads();
    for (int kt = 0; kt < 16; ++kt) {
        const unsigned short* Ac = (kt & 1) ? Ab1 : Ab0;
        const unsigned short* Bc = (kt & 1) ? Bb1 : Bb0;
        mfma_tile<32, 2, 2, 1>(Ac, Bc, acc, wr_, wc, lane);
        if (kt + 1 < 16) {
            unsigned short* An = (kt & 1) ? Ab0 : Ab1;
            unsigned short* Bn = (kt & 1) ? Bb0 : Bb1;
            ar.store(An, t); br.store(Bn, t);
            if (kt + 2 < 16) {
                ar.load(flow, 1024, i0, (kt + 2) * 64, t);
                br.load(wl1, 1024, 0, (kt + 2) * 64, t);
            }
        }
        __syncthreads();
    }
    proj_epilogue<128>(acc, YT1, Tg, i0, Tred, t);
}

// ---------------------------------------------------------------------------
// prep: blocks [0,32) proj1 -> YT1 + T1; blocks [32,352) weight cvt; scalar.
// ---------------------------------------------------------------------------
__global__ __launch_bounds__(256, 2)
void prep_kernel(const float* __restrict__ flow, const float* __restrict__ wl1,
                 const float* __restrict__ wr1, const float* __restrict__ wl2,
                 const float* __restrict__ wr2, const float* __restrict__ wl3,
                 const float* __restrict__ wr3, const float* __restrict__ wl4,
                 const float* __restrict__ wr4,
                 unsigned short* __restrict__ wbf,
                 unsigned short* __restrict__ YT1, float* __restrict__ T1,
                 float* __restrict__ outscalar)
{
    __shared__ unsigned short Ab0[32 * 64], Ab1[32 * 64];
    __shared__ unsigned short Bb0[128 * 64], Bb1[128 * 64];
    __shared__ float Tred[256];
    const int t = threadIdx.x, bid = blockIdx.x;
    if (bid >= 32) {
        if (bid == 32 && t == 0) outscalar[0] = 1.0f;
        int g = (bid - 32) * 1024 + t * 4;
        const float* src; int off;
        if      (g < 131072) { src = wr1; off = g; }
        else if (g < 163840) { src = wl2; off = g - 131072; }
        else if (g < 196608) { src = wr2; off = g - 163840; }
        else if (g < 229376) { src = wl3; off = g - 196608; }
        else if (g < 262144) { src = wr3; off = g - 229376; }
        else if (g < 294912) { src = wl4; off = g - 262144; }
        else                 { src = wr4; off = g - 294912; }
        float4 v = *reinterpret_cast<const float4*>(src + off);
        ushort4 o4;
        o4.x = f2bf(v.x); o4.y = f2bf(v.y); o4.z = f2bf(v.z); o4.w = f2bf(v.w);
        *reinterpret_cast<ushort4*>(wbf + g) = o4;
        return;
    }
    proj1_dbuf(flow, wl1, YT1, T1 + bid * 128, bid * 32, t,
               Ab0, Ab1, Bb0, Bb1, Tred);
}

// ---------------------------------------------------------------------------
// main_L.  MODE 1: bf16 x out (+ head: next-layer proj).  MODE 2: relu->fp32.
// DNEXT > 0: head blocks re-read their own just-stored x rows (post-barrier,
// L2) and run the staged proj for the next layer -> YTn + Tn.
// ---------------------------------------------------------------------------
template<int DOUT, int MODE, bool AFP32, int MINW, int DNEXT>
__global__ __launch_bounds__(256, MINW)
void mfma_gemm(const void* __restrict__ Xv,
               const unsigned short* __restrict__ W,
               const float* __restrict__ bias,
               const unsigned short* __restrict__ YT,  // (DOUT, 1024) bf16
               const float* __restrict__ Tbuf,         // (32, DOUT) fp32
               float* __restrict__ outf,
               unsigned short* __restrict__ outb,
               int din,
               const unsigned short* __restrict__ Wn,  // next wl (bf16)
               unsigned short* __restrict__ YTn, float* __restrict__ Tn)
{
    constexpr int BM = 32, BN = DOUT;
    constexpr int WN = DOUT / 64, WM = 4 / WN, FM = DOUT / 128;
    constexpr int BB = (DNEXT > BN ? DNEXT : BN);
    __shared__ unsigned short Abuf[BM * 64];
    __shared__ unsigned short Bbuf[BB * 64];
    __shared__ float ssred[WN * BM];
    __shared__ float Tred[256];

    const int t = threadIdx.x, wvid = t >> 6, lane = t & 63;
    const int wr_ = wvid / WN, wc = wvid % WN;
    const int i0 = blockIdx.x * BM;
    const int nt = din >> 6;
    const bool hasagg = (i0 < KROWS);

    f32x4 agg[FM][4];
#pragma unroll
    for (int fi = 0; fi < FM; ++fi)
#pragma unroll
        for (int fj = 0; fj < 4; ++fj) agg[fi][fj] = (f32x4){0.f, 0.f, 0.f, 0.f};

    if (hasagg) {
        // ---- P[col] = sum_{m'<m} T[m'][col] ----
        const int m = i0 >> 5;
        const int colb = wc * 64 + (lane & 15);
        float Pv[4] = {0.f, 0.f, 0.f, 0.f}, Pa[4] = {0.f, 0.f, 0.f, 0.f};
        int mp = 0;
        for (; mp + 1 < m; mp += 2) {
            const float* T0 = Tbuf + (size_t)mp * DOUT + colb;
            const float* T1p = T0 + DOUT;
#pragma unroll
            for (int fj = 0; fj < 4; ++fj) {
                Pv[fj] += T0[fj * 16];
                Pa[fj] += T1p[fj * 16];
            }
        }
        if (mp < m) {
            const float* T0 = Tbuf + (size_t)mp * DOUT + colb;
#pragma unroll
            for (int fj = 0; fj < 4; ++fj) Pv[fj] += T0[fj * 16];
        }
#pragma unroll
        for (int fj = 0; fj < 4; ++fj) Pv[fj] += Pa[fj];

        // ---- local triangular: ONE staged step over YT cols [base,base+64) -
        const int base = i0 & ~63;
        RegsBF<BN> sb;
        sb.load(YT, KROWS, 0, base, t);
        sb.store(Bbuf, t);
        __syncthreads();
#pragma unroll
        for (int kk = 0; kk < 2; ++kk) {
            const int jb = base + kk * 32 + ((lane >> 4) << 3);
            short8 a[FM], b[4];
#pragma unroll
            for (int fi = 0; fi < FM; ++fi) {
                const int irow = i0 + wr_ * (BM / WM) + fi * 16 + (lane & 15);
#pragma unroll
                for (int e = 0; e < 8; ++e)
                    a[fi][e] = (short)((jb + e >= i0 && jb + e < irow) ? 0x3F80 : 0);
            }
#pragma unroll
            for (int fj = 0; fj < 4; ++fj) {
                const int rB = wc * 64 + fj * 16 + (lane & 15);
                const int off = (rB * 128 + kk * 64 + (lane >> 4) * 16) ^ ((rB & 7) << 4);
                b[fj] = *reinterpret_cast<const short8*>((const char*)Bbuf + off);
            }
#pragma unroll
            for (int fi = 0; fi < FM; ++fi)
#pragma unroll
                for (int fj = 0; fj < 4; ++fj)
                    agg[fi][fj] = __builtin_amdgcn_mfma_f32_16x16x32_bf16(
                        a[fi], b[fj], agg[fi][fj], 0, 0, 0);
        }
#pragma unroll
        for (int fi = 0; fi < FM; ++fi)
#pragma unroll
            for (int reg = 0; reg < 4; ++reg) {
                const int i_abs = i0 + wr_ * (BM / WM) + fi * 16 + ((lane >> 4) << 2) + reg;
                const float inv = 1.0f / (float)(i_abs > 1 ? i_abs : 1);
#pragma unroll
                for (int fj = 0; fj < 4; ++fj)
                    agg[fi][fj][reg] = (agg[fi][fj][reg] + Pv[fj]) * inv;
            }
        __syncthreads();                        // Bbuf free before bulk
    }

    // ---- bulk GEMM (2-barrier staged core) ----
    f32x4 acc[FM][4];
#pragma unroll
    for (int fi = 0; fi < FM; ++fi)
#pragma unroll
        for (int fj = 0; fj < 4; ++fj) acc[fi][fj] = (f32x4){0.f, 0.f, 0.f, 0.f};

    RegsBF<BN> brg;
    RegsF32<BM> arf;
    RegsBF<BM> arb;
    if (AFP32) arf.load((const float*)Xv, din, i0, 0, t);
    else       arb.load((const unsigned short*)Xv, din, i0, 0, t);
    brg.load(W, din, 0, 0, t);

    for (int kt = 0; kt < nt; ++kt) {
        if (kt) __syncthreads();
        if (AFP32) arf.store(Abuf, t); else arb.store(Abuf, t);
        brg.store(Bbuf, t);
        __syncthreads();
        if (kt + 1 < nt) {
            int kn = (kt + 1) * 64;
            if (AFP32) arf.load((const float*)Xv, din, i0, kn, t);
            else       arb.load((const unsigned short*)Xv, din, i0, kn, t);
            brg.load(W, din, 0, kn, t);
        }
        mfma_tile<BM, WM, WN, FM>(Abuf, Bbuf, acc, wr_, wc, lane);
    }

    float bb[4];
#pragma unroll
    for (int fj = 0; fj < 4; ++fj) bb[fj] = bias[wc * 64 + fj * 16 + (lane & 15)];

#pragma unroll
    for (int fi = 0; fi < FM; ++fi)
#pragma unroll
        for (int fj = 0; fj < 4; ++fj)
#pragma unroll
            for (int reg = 0; reg < 4; ++reg)
                acc[fi][fj][reg] += bb[fj] + agg[fi][fj][reg];

    float sstot[FM][4];
#pragma unroll
    for (int fi = 0; fi < FM; ++fi)
#pragma unroll
        for (int reg = 0; reg < 4; ++reg) {
            float s = 0.f;
#pragma unroll
            for (int fj = 0; fj < 4; ++fj) {
                float v = acc[fi][fj][reg];
                s += v * v;
            }
#pragma unroll
            for (int m2 = 8; m2 >= 1; m2 >>= 1) s += __shfl_xor(s, m2);
            if ((lane & 15) == 0) {
                int rl = wr_ * (BM / WM) + fi * 16 + ((lane >> 4) << 2) + reg;
                ssred[wc * BM + rl] = s;
            }
        }
    __syncthreads();
#pragma unroll
    for (int fi = 0; fi < FM; ++fi)
#pragma unroll
        for (int reg = 0; reg < 4; ++reg) {
            int rl = wr_ * (BM / WM) + fi * 16 + ((lane >> 4) << 2) + reg;
            float s = 0.f;
#pragma unroll
            for (int c = 0; c < WN; ++c) s += ssred[c * BM + rl];
            sstot[fi][reg] = 1.0f / fmaxf(sqrtf(s), 1e-12f);
        }

#pragma unroll
    for (int fi = 0; fi < FM; ++fi)
#pragma unroll
        for (int fj = 0; fj < 4; ++fj)
#pragma unroll
            for (int reg = 0; reg < 4; ++reg) {
                int rl = wr_ * (BM / WM) + fi * 16 + ((lane >> 4) << 2) + reg;
                int cl = wc * 64 + fj * 16 + (lane & 15);
                float v = acc[fi][fj][reg] * sstot[fi][reg];
                if (MODE == 2) {
                    v = fmaxf(v, 0.f);
                    outf[(size_t)(i0 + rl) * DOUT + cl] = v;
                } else {
                    outb[(size_t)(i0 + rl) * DOUT + cl] = f2bf(v);
                }
            }

    // ---- head: next-layer proj on own just-stored rows ----
    if constexpr (DNEXT > 0) {
        if (hasagg) {
            __syncthreads();        // drain x stores (vmcnt0 at barrier)
            f32x4 acc2[DNEXT / 128][4];
            bulk_gemm_bf<DNEXT>(outb + (size_t)i0 * DOUT, Wn, acc2,
                                Abuf, Bbuf, DOUT, t);
            __syncthreads();        // Tred reuse safety (after ssred phase)
            proj_epilogue<DNEXT>(acc2, YTn, Tn + (i0 >> 5) * DNEXT, i0, Tred, t);
        }
    }
}

extern "C" void kernel_launch(void* const* d_in, const int* in_sizes, int n_in,
                              void* d_out, int out_size, void* d_ws, size_t ws_size,
                              hipStream_t stream)
{
    const float* flow = (const float*)d_in[0];
    const float* wl1 = (const float*)d_in[1];
    const float* bl1 = (const float*)d_in[2];
    const float* wr1 = (const float*)d_in[3];
    const float* wl2 = (const float*)d_in[4];
    const float* bl2 = (const float*)d_in[5];
    const float* wr2 = (const float*)d_in[6];
    const float* wl3 = (const float*)d_in[7];
    const float* bl3 = (const float*)d_in[8];
    const float* wr3 = (const float*)d_in[9];
    const float* wl4 = (const float*)d_in[10];
    const float* bl4 = (const float*)d_in[11];
    const float* wr4 = (const float*)d_in[12];
    float* out = (float*)d_out;

    char* p = (char*)d_ws;
    unsigned short* wbf = (unsigned short*)p;  p += 1 << 20;
    unsigned short* xA  = (unsigned short*)p;  p += (size_t)NROWS * 128 * 2;
    unsigned short* xB  = (unsigned short*)p;  p += (size_t)NROWS * 256 * 2;
    unsigned short* YT1 = (unsigned short*)p;  p += (size_t)128 * KROWS * 2;
    unsigned short* YT2 = (unsigned short*)p;  p += (size_t)256 * KROWS * 2;
    unsigned short* YT3 = (unsigned short*)p;  p += (size_t)128 * KROWS * 2;
    unsigned short* YT4 = (unsigned short*)p;  p += (size_t)256 * KROWS * 2;
    float* T1 = (float*)p;                     p += (size_t)32 * 128 * 4;
    float* T2 = (float*)p;                     p += (size_t)32 * 256 * 4;
    float* T3 = (float*)p;                     p += (size_t)32 * 128 * 4;
    float* T4 = (float*)p;

    const unsigned short* wr1b = wbf;
    const unsigned short* wl2b = wbf + 131072;
    const unsigned short* wr2b = wbf + 163840;
    const unsigned short* wl3b = wbf + 196608;
    const unsigned short* wr3b = wbf + 229376;
    const unsigned short* wl4b = wbf + 262144;
    const unsigned short* wr4b = wbf + 294912;

    // D1: cvt + proj1 (+ tuple scalar)
    prep_kernel<<<352, 256, 0, stream>>>(flow, wl1, wr1, wl2, wr2, wl3, wr3,
                                         wl4, wr4, wbf, YT1, T1,
                                         out + (size_t)NROWS * 256);
    // D2: main L1 (din=1024, fp32 A); heads emit proj2 -> YT2,T2
    mfma_gemm<128, 1, true , 4, 256><<<1024, 256, 0, stream>>>(
        flow, wr1b, bl1, YT1, T1, nullptr, xA, 1024, wl2b, YT2, T2);
    // D3: main L2 (din=128); heads emit proj3 -> YT3,T3
    mfma_gemm<256, 1, false, 3, 128><<<1024, 256, 0, stream>>>(
        xA, wr2b, bl2, YT2, T2, nullptr, xB, 128, wl3b, YT3, T3);
    // D4: main L3 (din=256); heads emit proj4 -> YT4,T4
    mfma_gemm<128, 1, false, 4, 256><<<1024, 256, 0, stream>>>(
        xB, wr3b, bl3, YT3, T3, nullptr, xA, 256, wl4b, YT4, T4);
    // D5: main L4 (din=128) + relu -> fp32 out
    mfma_gemm<256, 2, false, 3, 0><<<1024, 256, 0, stream>>>(
        xA, wr4b, bl4, YT4, T4, out, nullptr, 128, nullptr, nullptr, nullptr);
}